// Round 2
// baseline (136.492 us; speedup 1.0000x reference)
//
#include <hip/hip_runtime.h>
#include <math.h>

#define HF 37
#define WF 50
#define CC 512
#define POOLD 7
#define SAMPD 14

typedef float nfloat4 __attribute__((ext_vector_type(4)));

__device__ __forceinline__ float4 lerp4(float4 a, float4 b, float t) {
    float4 r;
    r.x = a.x + t * (b.x - a.x);
    r.y = a.y + t * (b.y - a.y);
    r.z = a.z + t * (b.z - a.z);
    r.w = a.w + t * (b.w - a.w);
    return r;
}

__device__ __forceinline__ float4 max4(float4 a, float4 b) {
    float4 r;
    r.x = fmaxf(a.x, b.x);
    r.y = fmaxf(a.y, b.y);
    r.z = fmaxf(a.z, b.z);
    r.w = fmaxf(a.w, b.w);
    return r;
}

__device__ __forceinline__ void store_nt4(float* p, float4 v) {
    nfloat4 nv;
    nv.x = v.x; nv.y = v.y; nv.z = v.z; nv.w = v.w;
    __builtin_nontemporal_store(nv, (nfloat4*)p);
}

// Raw (un-lerped) rows of one feature column.
// RC 0: rows ro0,ro1 shared by both sample rows. RC 1: ro0,ro1,ro3 (middle shared).
// RC 2: all four rows.
struct Raw { float4 a, b, c, d; };

template <int RC>
__device__ __forceinline__ Raw loadraw(const float* __restrict__ pbase, int col,
                                       int ro0, int ro1, int ro2, int ro3) {
    const float* p = pbase + (size_t)col * CC;
    Raw r;
    r.a = *(const float4*)(p + ro0);
    r.b = *(const float4*)(p + ro1);
    if (RC == 1) { r.c = *(const float4*)(p + ro3); }
    if (RC == 2) { r.c = *(const float4*)(p + ro2); r.d = *(const float4*)(p + ro3); }
    return r;
}

template <int RC>
__device__ __forceinline__ void vlerp(const Raw& r, float wya, float wyb,
                                      float4& va, float4& vb) {
    if (RC == 0)      { va = lerp4(r.a, r.b, wya); vb = lerp4(r.a, r.b, wyb); }
    else if (RC == 1) { va = lerp4(r.a, r.b, wya); vb = lerp4(r.b, r.c, wyb); }
    else              { va = lerp4(r.a, r.b, wya); vb = lerp4(r.c, r.d, wyb); }
}

// Fully unrolled straight-line sample loop. No column dedup cache (adjacent
// samples' repeated column loads are per-CU L1 hits; unique-line L2 traffic is
// unchanged), no data-dependent branches, rotating register slots give a
// software-pipeline of depth D so the compiler emits counted vmcnt waits.
template <int RC>
__device__ __forceinline__ void run_row(const float* __restrict__ pbase,
                                        float* __restrict__ obase,
                                        float nx1, float dx,
                                        int ro0, int ro1, int ro2, int ro3,
                                        float wya, float wyb)
{
    const float inv    = 1.0f / (float)(SAMPD - 1);
    const float wscale = (float)(WF - 1);
    // Prefetch depth chosen so slot registers stay under the 128-VGPR cap:
    // RC0: 4 slots * 4 float4 = 64 regs; RC1: 3 * 6 = 72; RC2: 2 * 8 = 64.
    constexpr int D     = (RC == 0) ? 3 : ((RC == 1) ? 2 : 1);
    constexpr int SLOTS = D + 1;

    Raw   ls[SLOTS], rs[SLOTS];
    float ws[SLOTS];

    float4 m0 = make_float4(-INFINITY, -INFINITY, -INFINITY, -INFINITY);

    #pragma unroll
    for (int i = 0; i < SAMPD + D; ++i) {
        if (i < SAMPD) {
            // sample descriptor (block-uniform -> scalar regs)
            float tx  = (float)i * inv;
            float xs  = fmaf(dx, tx, nx1) * wscale;
            xs        = fminf(fmaxf(xs, 0.0f), wscale);
            float x0f = floorf(xs);
            int c0 = __builtin_amdgcn_readfirstlane((int)x0f);
            int c1 = min(c0 + 1, WF - 1);
            ws[i % SLOTS] = xs - x0f;                                  // 0 at right edge
            ls[i % SLOTS] = loadraw<RC>(pbase, c0, ro0, ro1, ro2, ro3);
            rs[i % SLOTS] = loadraw<RC>(pbase, c1, ro0, ro1, ro2, ro3);
        }
        if (i >= D) {
            int k = i - D;
            int s = k % SLOTS;
            float4 va0, vb0, va1, vb1;
            vlerp<RC>(ls[s], wya, wyb, va0, vb0);
            vlerp<RC>(rs[s], wya, wyb, va1, vb1);
            float w  = ws[s];
            float4 sa = lerp4(va0, va1, w);
            float4 sb = lerp4(vb0, vb1, w);
            m0 = max4(m0, max4(sa, sb));
            if (k & 1) {
                store_nt4(obase + (size_t)(k >> 1) * CC, m0);
                m0 = make_float4(-INFINITY, -INFINITY, -INFINITY, -INFINITY);
            }
        }
    }
}

// One block per (roi, pooled_row). 128 threads * float4 = 512 channels.
__global__ __launch_bounds__(128, 4) void roipool_kernel(
    const float* __restrict__ feat,    // [HF, WF, CC]
    const float* __restrict__ rois,    // [N, 4] (x1,y1,x2,y2)
    const int*   __restrict__ im_size, // [2] (h, w)
    float*       __restrict__ out,     // [N, 7, 7, CC]
    int N)
{
    int bid = blockIdx.x;
    int n   = bid / POOLD;
    int py  = bid - n * POOLD;
    if (n >= N) return;

    float h = (float)im_size[0];
    float w = (float)im_size[1];
    float4 box = *(const float4*)(rois + 4 * n);
    float ny1 = box.y / h, nx1 = box.x / w;
    float ny2 = box.w / h, nx2 = box.z / w;
    float dx = nx2 - nx1;

    const float inv = 1.0f / (float)(SAMPD - 1);

    // vertical taps for the two sample rows of this pooled row (block-uniform)
    float tya = (float)(2 * py) * inv;
    float tyb = (float)(2 * py + 1) * inv;
    float ysa = (ny1 + (ny2 - ny1) * tya) * (float)(HF - 1);
    float ysb = (ny1 + (ny2 - ny1) * tyb) * (float)(HF - 1);
    ysa = fminf(fmaxf(ysa, 0.0f), (float)(HF - 1));
    ysb = fminf(fmaxf(ysb, 0.0f), (float)(HF - 1));
    float y0fa = floorf(ysa);
    float y0fb = floorf(ysb);
    float wya = ysa - y0fa;
    float wyb = ysb - y0fb;
    int iya = __builtin_amdgcn_readfirstlane((int)y0fa);
    int iyb = __builtin_amdgcn_readfirstlane((int)y0fb);
    int iya1 = min(iya + 1, HF - 1);
    int iyb1 = min(iyb + 1, HF - 1);
    int ro0 = iya  * (WF * CC);
    int ro1 = iya1 * (WF * CC);
    int ro2 = iyb  * (WF * CC);
    int ro3 = iyb1 * (WF * CC);

    const float* pbase = feat + (size_t)threadIdx.x * 4;
    float* obase = out + ((size_t)(n * POOLD + py) * POOLD) * CC + (size_t)threadIdx.x * 4;

    // Row-sharing case is fixed for the whole block -> one scalar dispatch.
    if (ro2 == ro0) {
        run_row<0>(pbase, obase, nx1, dx, ro0, ro1, ro2, ro3, wya, wyb);
    } else if (ro2 == ro1) {
        run_row<1>(pbase, obase, nx1, dx, ro0, ro1, ro2, ro3, wya, wyb);
    } else {
        run_row<2>(pbase, obase, nx1, dx, ro0, ro1, ro2, ro3, wya, wyb);
    }
}

extern "C" void kernel_launch(void* const* d_in, const int* in_sizes, int n_in,
                              void* d_out, int out_size, void* d_ws, size_t ws_size,
                              hipStream_t stream) {
    const float* feat    = (const float*)d_in[0];   // [1,37,50,512]
    const float* rois    = (const float*)d_in[1];   // [N,4]
    const int*   im_size = (const int*)d_in[2];     // [2]
    float* out = (float*)d_out;

    int N = in_sizes[1] / 4;
    int nblocks = N * POOLD;
    roipool_kernel<<<nblocks, 128, 0, stream>>>(feat, rois, im_size, out, N);
}